// Round 6
// baseline (313.356 us; speedup 1.0000x reference)
//
#include <hip/hip_runtime.h>
#include <math.h>

#define H 256
#define COLSN 64
#define ROWSN 200000
#define T_STEPS 4
#define QLEN 40
#define NNUM 5
#define NOPS 9

// workspace float offsets
#define WS_XWB    0          // 40*256 : X@Wx + b
#define WS_AOP    10240      // 4*16
#define WS_ACOL   10304      // 4*64
#define WS_PIV    10560      // [0]=g_pivot [1]=l_pivot
#define WS_TICKET 10568      // block completion ticket
#define WS_MOP    10752      // 9*256  : M_op[k][i]  = op_emb[k] . W_hc[i][:256]
#define WS_MCOL   13056      // 64*256 : M_col[c][i] = col_emb[c] . W_hc[i][256:]
#define WS_PACC   29440      // [8][32] : partial accum, k*32 + (blockIdx&31)

#define NTBL_BLOCKS 3125     // 3125 * 64 rows = 200000 exactly

// DPP-based partial-sum add (VALU pipe)
template<int CTRL>
__device__ __forceinline__ float dpp_add(float x) {
    int xi = __float_as_int(x);
    int yi = __builtin_amdgcn_update_dpp(0, xi, CTRL, 0xF, 0xF, true);
    return x + __int_as_float(yi);
}
#define DPP_XOR1 0xB1   // quad_perm [1,0,3,2]
#define DPP_XOR2 0x4E   // quad_perm [2,3,0,1]
#define DPP_HMIR 0x141  // row_half_mirror
#define DPP_MIR  0x140  // row_mirror

// 16-lane-group sum, result in all lanes of the group
__device__ __forceinline__ float reduce16(float v) {
    v = dpp_add<DPP_XOR1>(v);
    v = dpp_add<DPP_XOR2>(v);
    v = dpp_add<DPP_HMIR>(v);
    v = dpp_add<DPP_MIR>(v);
    return v;
}
// full 64-lane sum, result in all lanes
__device__ __forceinline__ float reduce64(float v) {
    v = reduce16(v);
    v += __shfl_xor(v, 16);
    v += __shfl_xor(v, 32);
    return v;
}

__device__ __forceinline__ float fast_tanh(float x) {
    float cx = fminf(15.f, fmaxf(-15.f, x));
    float e = __expf(2.f * cx);
    return __fdividef(e - 1.f, e + 1.f);
}

__device__ __forceinline__ float dot4(float4 a, float4 b) {
    return a.x * b.x + a.y * b.y + a.z * b.z + a.w * b.w;
}

// LDS swizzle: +4 floats pad per 16 -> 16-float slices start on distinct bank quads
__device__ __forceinline__ int sw(int i) { return i + ((i >> 4) << 2); }

// ==== k_pre: blocks 0..39 -> X@Wx+b ; blocks 40..47 -> M matrices ====
__global__ __launch_bounds__(256) void k_pre(const int* __restrict__ iq,
        const float* __restrict__ E, const float* __restrict__ Wx,
        const float* __restrict__ b, const float* __restrict__ W_hc,
        const float* __restrict__ op_emb, const float* __restrict__ col_emb,
        float* __restrict__ ws) {
    int blk = blockIdx.x;
    int tid = threadIdx.x;
    if (blk < QLEN) {
        if (blk == 0) {
            ws[WS_PACC + tid] = 0.f;        // 256 partials
            if (tid == 0) ws[WS_TICKET] = 0.f;
        }
        int word = iq[blk];
        const float* erow = E + (long)word * H;
        float acc = b[tid];
        #pragma unroll 8
        for (int j = 0; j < H; ++j) acc += erow[j] * Wx[j * H + tid];
        ws[WS_XWB + blk * H + tid] = acc;
    } else {
        __shared__ __attribute__((aligned(16))) float tile[32][516];
        int bi = blk - QLEN;          // 0..7
        int ibase = bi * 32;
        const float4* src = (const float4*)(W_hc + (long)ibase * 2 * H);
        for (int idx = tid; idx < 32 * 128; idx += 256) {
            int row = idx >> 7, c4 = idx & 127;
            *(float4*)&tile[row][c4 * 4] = src[idx];
        }
        __syncthreads();
        int l8 = tid & 7;
        int io = tid >> 3;            // 0..31
        for (int k = 0; k < NOPS + COLSN; ++k) {
            const float* emb = (k < NOPS) ? (op_emb + k * H) : (col_emb + (k - NOPS) * H);
            int coff = (k < NOPS) ? 0 : H;
            float s = 0.f;
            const float* ep = emb + l8 * 32;
            const float* tr = &tile[io][coff + l8 * 32];
            #pragma unroll
            for (int ss = 0; ss < 8; ++ss) {
                int q4 = (ss + io) & 7;
                float4 e4 = *(const float4*)&ep[q4 * 4];
                float4 t4 = *(const float4*)&tr[q4 * 4];
                s += dot4(e4, t4);
            }
            s += __shfl_xor(s, 1);
            s += __shfl_xor(s, 2);
            s += __shfl_xor(s, 4);
            if (l8 == 0) {
                int dst = (k < NOPS) ? (WS_MOP + k * H) : (WS_MCOL + (k - NOPS) * H);
                ws[dst + ibase + io] = s;
            }
        }
    }
}

// ==== k_main: question RNN + pivots + selector; 1 block x 1024 threads ====
// launch_bounds(1024, 1): grant the allocator the full 512-VGPR budget so the
// RNN's Wh fragment (64 VGPR) stays register-resident. LDS sized ~98 KB so
// only 1 block/CU fits (occupancy heuristic cannot target 2 blocks).
__global__ __launch_bounds__(1024, 1) void k_main(
        const float* __restrict__ Wh, const int* __restrict__ lwi,
        const float* __restrict__ U, const float* __restrict__ qn,
        const float* __restrict__ W_op, const float* __restrict__ W_col,
        const float* __restrict__ W_hh, const float* __restrict__ op_emb,
        const float* __restrict__ col_emb, float* __restrict__ ws) {
    __shared__ __attribute__((aligned(16))) float xwb[2 * QLEN][H];  // 80 KB (40 used)
    __shared__ __attribute__((aligned(16))) float hbuf[2][320];
    __shared__ __attribute__((aligned(16))) float qsw[320];
    __shared__ __attribute__((aligned(16))) float hhsw[320];
    __shared__ __attribute__((aligned(16))) float uopsw[320];
    __shared__ __attribute__((aligned(16))) float ucolsw[320];
    __shared__ float Z[NNUM][H];
    __shared__ float Pop[H], Pcol[H], vhh[H];
    __shared__ float lg[16];
    __shared__ float lgs[80];
    __shared__ float aop_s[16], acol_s[64];

    const int tid = threadIdx.x;      // 1024
    const int og = tid >> 4;          // 0..63
    const int p  = tid & 15;          // 0..15
    const int pb = p * 20;            // swizzled float base of slice p

    // ---- RNN weight fragment: w4[jj] = Wh[p*16+jj][og*4 .. og*4+3] ----
    float4 w4[16];
    #pragma unroll
    for (int jj = 0; jj < 16; ++jj)
        w4[jj] = *(const float4*)&Wh[(p * 16 + jj) * H + og * 4];

    // preload X@Wx+b into LDS; zero h buffers
    {
        const float4* src = (const float4*)&ws[WS_XWB];
        float4* dst = (float4*)&xwb[0][0];
        #pragma unroll 4
        for (int idx = tid; idx < QLEN * H / 4; idx += 1024) dst[idx] = src[idx];
    }
    if (tid < 320) { hbuf[0][tid] = 0.f; hbuf[1][tid] = 0.f; hhsw[tid] = 0.f; }
    __syncthreads();

    const int lw0 = lwi[0], lw1 = lwi[1], lw2 = lwi[2], lw3 = lwi[3], lw4 = lwi[4];
    int cur = 0;
    for (int t = 0; t < QLEN; ++t) {
        const float* hb = hbuf[cur];
        float4 h0 = *(const float4*)&hb[pb + 0];
        float4 h1 = *(const float4*)&hb[pb + 4];
        float4 h2 = *(const float4*)&hb[pb + 8];
        float4 h3 = *(const float4*)&hb[pb + 12];
        float a0 = 0.f, a1 = 0.f, a2 = 0.f, a3 = 0.f;
        #define RNN_FMA(hv, e, jj) \
            a0 += hv.e * w4[jj].x; a1 += hv.e * w4[jj].y; \
            a2 += hv.e * w4[jj].z; a3 += hv.e * w4[jj].w;
        RNN_FMA(h0, x, 0)  RNN_FMA(h0, y, 1)  RNN_FMA(h0, z, 2)  RNN_FMA(h0, w, 3)
        RNN_FMA(h1, x, 4)  RNN_FMA(h1, y, 5)  RNN_FMA(h1, z, 6)  RNN_FMA(h1, w, 7)
        RNN_FMA(h2, x, 8)  RNN_FMA(h2, y, 9)  RNN_FMA(h2, z, 10) RNN_FMA(h2, w, 11)
        RNN_FMA(h3, x, 12) RNN_FMA(h3, y, 13) RNN_FMA(h3, z, 14) RNN_FMA(h3, w, 15)
        #undef RNN_FMA
        a0 = reduce16(a0); a1 = reduce16(a1); a2 = reduce16(a2); a3 = reduce16(a3);
        if (p < 4) {
            float s = (p == 0) ? a0 : (p == 1) ? a1 : (p == 2) ? a2 : a3;
            int i = og * 4 + p;
            float hn = fast_tanh(xwb[t][i] + s);
            hbuf[cur ^ 1][sw(i)] = hn;
            if (t == lw0) Z[0][i] = hn;
            if (t == lw1) Z[1][i] = hn;
            if (t == lw2) Z[2][i] = hn;
            if (t == lw3) Z[3][i] = hn;
            if (t == lw4) Z[4][i] = hn;
        }
        __syncthreads();
        cur ^= 1;
    }
    if (tid < 320) qsw[tid] = hbuf[cur][tid];

    // pivot logits: 10 dots of 256
    {
        int grp = tid >> 5, lane = tid & 31;
        if (grp < 10) {
            int u = grp / 5, n = grp % 5;
            float s = 0.f;
            #pragma unroll
            for (int k = 0; k < 8; ++k) {
                int j = lane + k * 32;
                s += Z[n][j] * U[u * H + j];
            }
            s += __shfl_xor(s, 1);
            s += __shfl_xor(s, 2);
            s += __shfl_xor(s, 4);
            s += __shfl_xor(s, 8);
            s += __shfl_xor(s, 16);
            if (lane == 0) lg[grp] = s;
        }
    }
    __syncthreads();
    if (tid < 2) {
        float m = -1e30f;
        for (int n = 0; n < 5; ++n) m = fmaxf(m, lg[tid * 5 + n]);
        float e[5], s = 0.f;
        for (int n = 0; n < 5; ++n) { e[n] = expf(lg[tid * 5 + n] - m); s += e[n]; }
        float piv = 0.f;
        for (int n = 0; n < 5; ++n) piv += (e[n] / s) * qn[n];
        ws[WS_PIV + (tid == 0 ? 1 : 0)] = piv;   // PIV[0]=g, PIV[1]=l
    }

    // prologue: P_op / P_col = W[:, :256] @ q  (streamed once)
    {
        float4 q0 = *(const float4*)&qsw[pb + 0];
        float4 q1 = *(const float4*)&qsw[pb + 4];
        float4 q2 = *(const float4*)&qsw[pb + 8];
        float4 q3 = *(const float4*)&qsw[pb + 12];
        #pragma unroll 2
        for (int mm = 0; mm < 8; ++mm) {
            int o = og + (mm & 3) * 64;
            const float* row = (mm < 4) ? &W_op[(long)o * 2 * H + p * 16]
                                        : &W_col[(long)o * 2 * H + p * 16];
            float4 r0 = *(const float4*)&row[0];
            float4 r1 = *(const float4*)&row[4];
            float4 r2 = *(const float4*)&row[8];
            float4 r3 = *(const float4*)&row[12];
            float s = dot4(r0, q0) + dot4(r1, q1) + dot4(r2, q2) + dot4(r3, q3);
            s = reduce16(s);
            if (p == 0) { if (mm < 4) Pop[o] = s; else Pcol[o] = s; }
        }
    }
    __syncthreads();

    // ---- selector timesteps (weights streamed from L2 each step) ----
    for (int t = 0; t < T_STEPS; ++t) {
        // stage A: u_op, u_col, vhh = {W_op2, W_col2, W_hh} @ h
        {
            float4 h0 = *(const float4*)&hhsw[pb + 0];
            float4 h1 = *(const float4*)&hhsw[pb + 4];
            float4 h2 = *(const float4*)&hhsw[pb + 8];
            float4 h3 = *(const float4*)&hhsw[pb + 12];
            #pragma unroll 2
            for (int m = 0; m < 12; ++m) {
                int o = og + (m & 3) * 64;
                const float* row;
                if (m < 4)      row = &W_op[(long)o * 2 * H + H + p * 16];
                else if (m < 8) row = &W_col[(long)o * 2 * H + H + p * 16];
                else            row = &W_hh[(long)o * H + p * 16];
                float4 r0 = *(const float4*)&row[0];
                float4 r1 = *(const float4*)&row[4];
                float4 r2 = *(const float4*)&row[8];
                float4 r3 = *(const float4*)&row[12];
                float s = dot4(r0, h0) + dot4(r1, h1) + dot4(r2, h2) + dot4(r3, h3);
                s = reduce16(s);
                if (p == 0) {
                    if (m < 4)      uopsw[sw(o)] = fast_tanh(Pop[o] + s);
                    else if (m < 8) ucolsw[sw(o)] = fast_tanh(Pcol[o] + s);
                    else            vhh[o] = s;
                }
            }
        }
        __syncthreads();
        // logits: 73 dots of 256 (emb rows streamed; they stay hot in L1/L2)
        {
            float4 uc0 = *(const float4*)&ucolsw[pb + 0];
            float4 uc1 = *(const float4*)&ucolsw[pb + 4];
            float4 uc2 = *(const float4*)&ucolsw[pb + 8];
            float4 uc3 = *(const float4*)&ucolsw[pb + 12];
            const float* crow = &col_emb[og * H + p * 16];
            float4 e0 = *(const float4*)&crow[0];
            float4 e1 = *(const float4*)&crow[4];
            float4 e2 = *(const float4*)&crow[8];
            float4 e3 = *(const float4*)&crow[12];
            float s = dot4(e0, uc0) + dot4(e1, uc1) + dot4(e2, uc2) + dot4(e3, uc3);
            s = reduce16(s);
            if (p == 0) lgs[NOPS + og] = s;
            if (og < NOPS) {
                float4 uo0 = *(const float4*)&uopsw[pb + 0];
                float4 uo1 = *(const float4*)&uopsw[pb + 4];
                float4 uo2 = *(const float4*)&uopsw[pb + 8];
                float4 uo3 = *(const float4*)&uopsw[pb + 12];
                const float* orow = &op_emb[og * H + p * 16];
                float4 f0 = *(const float4*)&orow[0];
                float4 f1 = *(const float4*)&orow[4];
                float4 f2 = *(const float4*)&orow[8];
                float4 f3 = *(const float4*)&orow[12];
                float so = dot4(f0, uo0) + dot4(f1, uo1) + dot4(f2, uo2) + dot4(f3, uo3);
                so = reduce16(so);
                if (p == 0) lgs[og] = so;
            }
        }
        __syncthreads();
        // softmaxes
        if (tid == 0) {
            float m = -1e30f;
            for (int k = 0; k < NOPS; ++k) m = fmaxf(m, lgs[k]);
            float e[NOPS], s = 0.f;
            for (int k = 0; k < NOPS; ++k) { e[k] = expf(lgs[k] - m); s += e[k]; }
            float inv = 1.f / s;
            for (int k = 0; k < NOPS; ++k) {
                float a = e[k] * inv;
                aop_s[k] = a;
                ws[WS_AOP + t * 16 + k] = a;
            }
        }
        if (tid >= 64 && tid < 128) {
            int lane = tid - 64;
            float v = lgs[NOPS + lane];
            float m = v;
            for (int off = 1; off < 64; off <<= 1) m = fmaxf(m, __shfl_xor(m, off));
            float e = expf(v - m);
            float s = e;
            for (int off = 1; off < 64; off <<= 1) s += __shfl_xor(s, off);
            float a = __fdividef(e, s);
            acol_s[lane] = a;
            ws[WS_ACOL + t * COLSN + lane] = a;
        }
        __syncthreads();
        // h-update: h = tanh(vhh + M_op^T a_op + M_col^T a_col)
        if (tid < H) {
            float s = vhh[tid];
            const float* mop = &ws[WS_MOP + tid];
            #pragma unroll
            for (int k = 0; k < NOPS; ++k) s += aop_s[k] * mop[k * H];
            const float* mcol = &ws[WS_MCOL + tid];
            #pragma unroll 8
            for (int c = 0; c < COLSN; ++c) s += acol_s[c] * mcol[c * H];
            hhsw[sw(tid)] = fast_tanh(s);
        }
        __syncthreads();
    }
}

// ==== k_table: 64-thread blocks, one 64-row tile each; stride-65 LDS
// ==== transpose, acol pre-transposed to [c][t] (1 uniform b128/col),
// ==== uniform-row write phase, banked partial atomics, ticketed tail.
__global__ __launch_bounds__(64) void k_table(const float* __restrict__ table,
                                              float* __restrict__ ws,
                                              float* __restrict__ out) {
    __shared__ __attribute__((aligned(16))) float tile[64 * 65];   // 16.6 KB
    __shared__ __attribute__((aligned(16))) float acT[4 * COLSN];  // [c][t]
    __shared__ float aop_l[64];
    __shared__ float rs3s[64];
    const int lane = threadIdx.x;

    aop_l[lane] = ws[WS_AOP + lane];
    #pragma unroll
    for (int j = 0; j < 4; ++j)
        acT[lane * 4 + j] = ws[WS_ACOL + j * COLSN + lane];
    float gp = ws[WS_PIV + 0];
    float lp = ws[WS_PIV + 1];

    long base = (long)blockIdx.x * 64;
    const float* src = table + base * COLSN;
    #pragma unroll
    for (int s = 0; s < 16; ++s) {
        float4 v = *(const float4*)(src + s * 256 + lane * 4);
        int row = s * 4 + (lane >> 4);
        int col = (lane & 15) * 4;
        float* d = &tile[row * 65 + col];
        d[0] = v.x; d[1] = v.y; d[2] = v.z; d[3] = v.w;
    }
    __syncthreads();

    // per-lane row: stride-65 scalar reads = 2 lanes/bank (free)
    const float* tr = &tile[lane * 65];
    float cv[4] = {0,0,0,0}, gs[4] = {0,0,0,0}, ls[4] = {0,0,0,0};
    #pragma unroll 8
    for (int c = 0; c < COLSN; ++c) {
        float x = tr[c];
        float4 a4 = *(const float4*)&acT[c * 4];   // wave-uniform b128
        float gt = (x > gp) ? 1.f : 0.f;
        float lt = (x < lp) ? 1.f : 0.f;
        cv[0] += x * a4.x;  cv[1] += x * a4.y;  cv[2] += x * a4.z;  cv[3] += x * a4.w;
        gs[0] += gt * a4.x; gs[1] += gt * a4.y; gs[2] += gt * a4.z; gs[3] += gt * a4.w;
        ls[0] += lt * a4.x; ls[1] += lt * a4.y; ls[2] += lt * a4.z; ls[3] += lt * a4.w;
    }

    float prev1 = 1.f, prev2 = 1.f;
    float dotp[4], cntp[4];
    #pragma unroll
    for (int t = 0; t < 4; ++t) {
        dotp[t] = prev1 * cv[t];
        cntp[t] = prev1;
        float cg = aop_l[t*16+3], cl = aop_l[t*16+4], cmn = aop_l[t*16+5];
        float cmx = aop_l[t*16+6], co = aop_l[t*16+8];
        float cid = aop_l[t*16+0] + aop_l[t*16+1] + aop_l[t*16+2] + aop_l[t*16+7];
        float rsn = cg * gs[t] + cl * ls[t] + cmn * fminf(prev1, prev2)
                  + cmx * fmaxf(prev1, prev2) + co + cid * prev1;
        prev2 = prev1; prev1 = rsn;
    }
    rs3s[lane] = prev1 * aop_l[3*16+7];
    __syncthreads();

    // lookup write: row s is wave-uniform -> 1 LDS read + 1 mul + 256B store
    {
        float ac3 = acT[lane * 4 + 3];
        float* dst = out + 1 + base * COLSN;
        #pragma unroll 8
        for (int s = 0; s < 64; ++s)
            dst[s * COLSN + lane] = rs3s[s] * ac3;
    }

    // wave-reduce the 8 accumulators, banked atomics
    float vals[8];
    #pragma unroll
    for (int t = 0; t < 4; ++t) { vals[t] = dotp[t]; vals[4 + t] = cntp[t]; }
    #pragma unroll
    for (int k = 0; k < 8; ++k) vals[k] = reduce64(vals[k]);
    if (lane == 0) {
        int bank = blockIdx.x & 31;
        #pragma unroll
        for (int k = 0; k < 8; ++k)
            atomicAdd(&ws[WS_PACC + k * 32 + bank], vals[k]);
    }
    __syncthreads();   // drains vmcnt (atomics) before ticket

    if (lane == 0) {
        float old = atomicAdd(&ws[WS_TICKET], 1.0f);
        if ((int)(old + 0.5f) == NTBL_BLOCKS - 1) {
            float acc[8];
            #pragma unroll
            for (int k = 0; k < 8; ++k) {
                float s = 0.f;
                for (int bnk = 0; bnk < 32; ++bnk)
                    s += atomicAdd(&ws[WS_PACC + k * 32 + bnk], 0.f);
                acc[k] = s;
            }
            float s0 = aop_l[0]*acc[0]  + aop_l[1]*acc[4];
            float s1 = aop_l[16]*acc[1] + aop_l[17]*acc[5] + aop_l[18]*(0.f - s0);
            float s2 = aop_l[32]*acc[2] + aop_l[33]*acc[6] + aop_l[34]*(0.f - s1);
            float s3 = aop_l[48]*acc[3] + aop_l[49]*acc[7] + aop_l[50]*(s0 - s2);
            out[0] = s3;
        }
    }
}

extern "C" void kernel_launch(void* const* d_in, const int* in_sizes, int n_in,
                              void* d_out, int out_size, void* d_ws, size_t ws_size,
                              hipStream_t stream) {
    const int*   iq      = (const int*)  d_in[0];
    const float* qn      = (const float*)d_in[1];
    const int*   lwi     = (const int*)  d_in[2];
    const float* table   = (const float*)d_in[3];
    const float* E       = (const float*)d_in[4];
    const float* Wx      = (const float*)d_in[5];
    const float* Wh      = (const float*)d_in[6];
    const float* b       = (const float*)d_in[7];
    const float* W_op    = (const float*)d_in[8];
    const float* op_emb  = (const float*)d_in[9];
    const float* W_col   = (const float*)d_in[10];
    const float* col_emb = (const float*)d_in[11];
    const float* U       = (const float*)d_in[12];
    const float* W_hc    = (const float*)d_in[13];
    const float* W_hh    = (const float*)d_in[14];
    float* out = (float*)d_out;
    float* ws  = (float*)d_ws;

    hipLaunchKernelGGL(k_pre,  dim3(QLEN + 8), dim3(256), 0, stream,
                       iq, E, Wx, b, W_hc, op_emb, col_emb, ws);
    hipLaunchKernelGGL(k_main, dim3(1), dim3(1024), 0, stream,
                       Wh, lwi, U, qn, W_op, W_col, W_hh, op_emb, col_emb, ws);
    hipLaunchKernelGGL(k_table, dim3(NTBL_BLOCKS), dim3(64), 0, stream,
                       table, ws, out);
}